// Round 9
// baseline (363.567 us; speedup 1.0000x reference)
//
#include <hip/hip_runtime.h>

#define HIDDEN 64
#define INFEAT 128
#define SCALE_C 0.70710678118654752f
#define BN_EPS 1e-5f
#define AGG_GRID 2048
#define RED_BLK 32

// ---------- lane broadcast helper (uniform lane index) ----------
__device__ __forceinline__ float rlf(float v, int l){
  return __int_as_float(__builtin_amdgcn_readlane(__float_as_int(v), l));
}

// ---------- GEMM body: 64-row tile, Y[N][64] = X[N][KDIM] @ W (+B); opt fused T = Y @ W2 ----------
// 4 waves: wave w owns cols [w*16, w*16+16), row = lane. LDS 64x65 f32 (16.6KB).
template<int KDIM, bool ADDB, bool FUSET>
__device__ __forceinline__ void gemm_body(int bid, const float* __restrict__ X,
    const float* __restrict__ W, const float* __restrict__ B,
    float* __restrict__ Y, const float* __restrict__ W2, float* __restrict__ T, int N)
{
  __shared__ float smem[64 * 65];
  const int tid  = threadIdx.x;
  const int lane = tid & 63;
  const int wid  = __builtin_amdgcn_readfirstlane(tid >> 6);  // wave-uniform
  const int c0 = wid * 16;
  const int base = bid * 64;
  const int gnode = base + lane;

  float acc[16];
  #pragma unroll
  for (int c = 0; c < 16; ++c) acc[c] = ADDB ? B[c0 + c] : 0.f;

  constexpr int NCHUNK = KDIM / 32;
  #pragma unroll 1
  for (int ck = 0; ck < NCHUNK; ++ck){
    __syncthreads();
    #pragma unroll
    for (int i = 0; i < 2; ++i){
      int f  = i * 256 + tid;        // float4 id, 0..511
      int nd = f >> 3;               // 0..63
      int kq = f & 7;                // 0..7
      float4 v = make_float4(0.f, 0.f, 0.f, 0.f);
      if (base + nd < N)
        v = *(const float4*)(X + (size_t)(base + nd) * KDIM + ck * 32 + kq * 4);
      float* p = &smem[nd * 65 + kq * 4];
      p[0] = v.x; p[1] = v.y; p[2] = v.z; p[3] = v.w;
    }
    __syncthreads();
    const float* wrow = W + (size_t)ck * 32 * HIDDEN + c0;   // uniform base -> s_load
    #pragma unroll
    for (int k = 0; k < 32; ++k){
      float xv = smem[lane * 65 + k];       // bank (lane+k)%32: conflict-free
      #pragma unroll
      for (int c = 0; c < 16; ++c)
        acc[c] = fmaf(xv, wrow[k * HIDDEN + c], acc[c]);
    }
  }

  if (gnode < N){
    float4* yp = (float4*)(Y + (size_t)gnode * HIDDEN + c0);
    #pragma unroll
    for (int j = 0; j < 4; ++j)
      yp[j] = make_float4(acc[4*j], acc[4*j+1], acc[4*j+2], acc[4*j+3]);
  }

  if constexpr (FUSET){
    // h-tile exchange through the same 64x65 buffer, then T = h @ W2
    __syncthreads();                 // chunk-loop reads done
    #pragma unroll
    for (int c = 0; c < 16; ++c) smem[lane * 65 + c0 + c] = acc[c];
    __syncthreads();
    float tacc[16];
    #pragma unroll
    for (int c = 0; c < 16; ++c) tacc[c] = 0.f;
    const float* w2r = W2 + c0;
    #pragma unroll
    for (int k = 0; k < 64; ++k){
      float hv = smem[lane * 65 + k];
      #pragma unroll
      for (int c = 0; c < 16; ++c)
        tacc[c] = fmaf(hv, w2r[k * HIDDEN + c], tacc[c]);
    }
    if (gnode < N){
      float4* tp = (float4*)(T + (size_t)gnode * HIDDEN + c0);
      #pragma unroll
      for (int j = 0; j < 4; ++j)
        tp[j] = make_float4(tacc[4*j], tacc[4*j+1], tacc[4*j+2], tacc[4*j+3]);
    }
  }
}

// Bresenham role spread
__device__ __forceinline__ int role_gemm_idx(int b, int GB, int TOT, int& histIdx){
  int fb  = (int)(((long)b * GB) / TOT);
  int fb1 = (int)(((long)(b + 1) * GB) / TOT);
  histIdx = b - fb;
  return (fb1 > fb) ? fb : -1;
}

// ---------- mega1: degI hist (fire-and-forget, 8 edges/thread) || fc GEMM + fused gemm1 ----------
__global__ __launch_bounds__(256) void k_mega1(const int* __restrict__ dst,
    int* __restrict__ degI, int E,
    const float* __restrict__ x, const float* __restrict__ fc_w,
    const float* __restrict__ fc_b, float* __restrict__ h,
    const float* __restrict__ w1, float* __restrict__ t, int N, int GB, int TOT){
  int hIdx;
  int g = role_gemm_idx(blockIdx.x, GB, TOT, hIdx);
  if (g >= 0) gemm_body<INFEAT, true, true>(g, x, fc_w, fc_b, h, w1, t, N);
  else {
    int e0 = hIdx * 2048 + threadIdx.x;
    #pragma unroll
    for (int i = 0; i < 8; ++i){
      int e = e0 + i * 256;
      if (e < E) atomicAdd(&degI[dst[e]], 1);   // no return value: fire-and-forget
    }
  }
}

// ---------- place: rank-free CSR scatter via cursor bump + degO histogram (8/thread) ----------
__global__ __launch_bounds__(256) void k_place(const int* __restrict__ src,
    const int* __restrict__ dst, int* __restrict__ cursor,
    int* __restrict__ cs, int* __restrict__ degO, int E){
  int e0 = blockIdx.x * 2048 + threadIdx.x;
  #pragma unroll
  for (int i = 0; i < 8; ++i){
    int e = e0 + i * 256;
    if (e < E){
      int s = src[e];
      int pos = atomicAdd(&cursor[dst[e]], 1);   // slot = old cursor (rp-initialized)
      cs[pos] = s;
      atomicAdd(&degO[s], 1);
    }
  }
}

// ---------- scan step 1 ----------
__global__ void k_scan1(const int* __restrict__ deg, int* __restrict__ bsum, int N){
  __shared__ int sh[256];
  int t = threadIdx.x;
  int i = blockIdx.x * 256 + t;
  sh[t] = (i < N) ? deg[i] : 0;
  __syncthreads();
  for (int ofs = 128; ofs > 0; ofs >>= 1){
    if (t < ofs) sh[t] += sh[t + ofs];
    __syncthreads();
  }
  if (t == 0) bsum[blockIdx.x] = sh[0];
}

// ---------- scan step 2 ----------
__global__ void k_scan2(int* __restrict__ bsum, int NB){
  __shared__ int sh[512];
  int t = threadIdx.x;
  int v = (t < NB) ? bsum[t] : 0;
  sh[t] = v;
  __syncthreads();
  for (int ofs = 1; ofs < 512; ofs <<= 1){
    int u = (t >= ofs) ? sh[t - ofs] : 0;
    __syncthreads();
    sh[t] += u;
    __syncthreads();
  }
  if (t < NB) bsum[t] = sh[t] - v;   // exclusive
}

// ---------- scan step 3: rp + cursor copy + norm_in ----------
__global__ void k_scan3(const int* __restrict__ degI, const int* __restrict__ bofs,
                        int* __restrict__ rp, int* __restrict__ cursor,
                        float* __restrict__ norm_in, int N, int E){
  __shared__ int sh[256];
  int t = threadIdx.x;
  int i = blockIdx.x * 256 + t;
  int v = (i < N) ? degI[i] : 0;
  sh[t] = v;
  __syncthreads();
  for (int ofs = 1; ofs < 256; ofs <<= 1){
    int u = (t >= ofs) ? sh[t - ofs] : 0;
    __syncthreads();
    sh[t] += u;
    __syncthreads();
  }
  if (i < N){
    int excl = sh[t] - v + bofs[blockIdx.x];
    rp[i] = excl;
    cursor[i] = excl;          // place's bump-allocator start
    if (i == N - 1) rp[N] = E;
    norm_in[i] = rsqrtf((float)max(v, 1));
  }
}

// ---------- float4 gather, 4 prefetched cs slots (covers deg<=16 without exposed cs chain) ----------
// 16-lane group g owns slots start+g+8k (+4 partner). i0..i3 = cs at slots g,g+4,g+8,g+12,
// prefetched one node ahead by the caller. PRE=false folds rsqrt(degO[src]); PRE=true plain sum.
template<bool PRE>
__device__ __forceinline__ float4 gather_pre4(const int* __restrict__ cs,
    const float* __restrict__ t, const int* __restrict__ degO,
    int start, int end, int g, int s4, int i0, int i1, int i2, int i3)
{
  float4 acc = make_float4(0.f, 0.f, 0.f, 0.f);
  int j0 = start + g;                  // per-lane-group position; divergent, exec-masked
  if (j0 >= end) return acc;
  {                                    // iter 1: slots g, g+4 (prefetched)
    const bool b1 = (j0 + 4 < end);
    const float4 r0 = *(const float4*)(t + (size_t)i0 * HIDDEN + s4);
    const float4 r1 = *(const float4*)(t + (size_t)i1 * HIDDEN + s4);
    const float w0 = PRE ? 1.f : rsqrtf((float)degO[i0]);
    const float w1 = b1 ? (PRE ? 1.f : rsqrtf((float)degO[i1])) : 0.f;
    acc.x = fmaf(r0.x, w0, acc.x); acc.y = fmaf(r0.y, w0, acc.y);
    acc.z = fmaf(r0.z, w0, acc.z); acc.w = fmaf(r0.w, w0, acc.w);
    acc.x = fmaf(r1.x, w1, acc.x); acc.y = fmaf(r1.y, w1, acc.y);
    acc.z = fmaf(r1.z, w1, acc.z); acc.w = fmaf(r1.w, w1, acc.w);
    j0 += 8;
  }
  if (j0 >= end) return acc;
  {                                    // iter 2: slots g+8, g+12 (prefetched)
    const bool b1 = (j0 + 4 < end);
    const float4 r0 = *(const float4*)(t + (size_t)i2 * HIDDEN + s4);
    const float4 r1 = *(const float4*)(t + (size_t)i3 * HIDDEN + s4);
    const float w0 = PRE ? 1.f : rsqrtf((float)degO[i2]);
    const float w1 = b1 ? (PRE ? 1.f : rsqrtf((float)degO[i3])) : 0.f;
    acc.x = fmaf(r0.x, w0, acc.x); acc.y = fmaf(r0.y, w0, acc.y);
    acc.z = fmaf(r0.z, w0, acc.z); acc.w = fmaf(r0.w, w0, acc.w);
    acc.x = fmaf(r1.x, w1, acc.x); acc.y = fmaf(r1.y, w1, acc.y);
    acc.z = fmaf(r1.z, w1, acc.z); acc.w = fmaf(r1.w, w1, acc.w);
    j0 += 8;
  }
  while (j0 < end){                    // tail (deg>16, ~2.6% of nodes): inline cs loads
    int a0 = cs[j0];
    int a1 = (j0 + 4 < end) ? cs[j0 + 4] : a0;
    const bool b1 = (j0 + 4 < end);
    const float4 r0 = *(const float4*)(t + (size_t)a0 * HIDDEN + s4);
    const float4 r1 = *(const float4*)(t + (size_t)a1 * HIDDEN + s4);
    const float w0 = PRE ? 1.f : rsqrtf((float)degO[a0]);
    const float w1 = b1 ? (PRE ? 1.f : rsqrtf((float)degO[a1])) : 0.f;
    acc.x = fmaf(r0.x, w0, acc.x); acc.y = fmaf(r0.y, w0, acc.y);
    acc.z = fmaf(r0.z, w0, acc.z); acc.w = fmaf(r0.w, w0, acc.w);
    acc.x = fmaf(r1.x, w1, acc.x); acc.y = fmaf(r1.y, w1, acc.y);
    acc.z = fmaf(r1.z, w1, acc.z); acc.w = fmaf(r1.w, w1, acc.w);
    j0 += 8;
  }
  return acc;
}

// prefetch the 4 leading cs slots of a bucket (clamped to safe index 0, weight applied later)
__device__ __forceinline__ void pf4(const int* __restrict__ cs, int s, int e, int g,
                                    int& p0, int& p1, int& p2, int& p3){
  p0 = (s + g      < e) ? cs[s + g]      : 0;
  p1 = (s + g + 4  < e) ? cs[s + g + 4]  : 0;
  p2 = (s + g + 8  < e) ? cs[s + g + 8]  : 0;
  p3 = (s + g + 12 < e) ? cs[s + g + 12] : 0;
}

// cross-group butterfly: after this, every lane holds the full row sum for its channel-quad
__device__ __forceinline__ float4 xreduce4(float4 a){
  #pragma unroll
  for (int m = 16; m <= 32; m <<= 1){
    a.x += __shfl_xor(a.x, m, 64);
    a.y += __shfl_xor(a.y, m, 64);
    a.z += __shfl_xor(a.z, m, 64);
    a.w += __shfl_xor(a.w, m, 64);
  }
  return a;
}

// ---------- fused CSR aggregate + residual (+ BN partials) (+ fused t2 = (h1@w2)*norm_out) ----------
// Node pipeline: A = current (ctx ready), B = next (rp ready; cs/norm/h issued this iter),
// C = next-next (rp in flight). Breaks the per-node rp->cs->row chain across nodes.
template<bool BN, bool PRE, bool FUSET2>
__global__ __launch_bounds__(256, 4) void k_agg(const int* __restrict__ rp, const int* __restrict__ cs,
    const float* __restrict__ t, const int* __restrict__ degO,
    const float* __restrict__ norm_in, const float* __restrict__ b,
    const float* __restrict__ w2, float* __restrict__ h,
    float* __restrict__ t2, float* __restrict__ bnpart, int N)
{
  const int tid  = threadIdx.x;
  const int lane = tid & 63;
  const int g    = lane >> 4;        // edge-slot group 0..3
  const int s    = lane & 15;        // channel-quad 0..15
  const int s4   = s * 4;
  const int wv = (blockIdx.x * 256 + tid) >> 6;
  const int nw = (gridDim.x * 256) >> 6;
  const float4 bv = ((const float4*)b)[s];
  float4 s1 = make_float4(0.f,0.f,0.f,0.f), s2v = make_float4(0.f,0.f,0.f,0.f);

  // fastest measured epilogue form (r4): w2 column kept as VGPR array; compiler remats
  // the loads but they are L1-resident (LDS-staged variant was slower, r6).
  float w2c[64];
  if constexpr (FUSET2){
    #pragma unroll
    for (int k = 0; k < 64; ++k) w2c[k] = w2[k * HIDDEN + lane];
  }

  // ---- pipeline prologue ----
  int nA = wv;
  int sA = 0, eA = 0, pA0 = 0, pA1 = 0, pA2 = 0, pA3 = 0; float niA = 0.f;
  float4 hA = make_float4(0.f,0.f,0.f,0.f);
  if (nA < N){
    sA = rp[nA]; eA = rp[nA + 1];
    niA = norm_in[nA];
    hA = *(const float4*)(h + (size_t)nA * HIDDEN + s4);
    pf4(cs, sA, eA, g, pA0, pA1, pA2, pA3);
  }
  int nB = nA + nw;
  int sB = 0, eB = 0;
  if (nB < N){ sB = rp[nB]; eB = rp[nB + 1]; }

  for (int n = nA; n < N; n += nw){
    // issue rp for node C (two ahead) — independent, hides under this gather
    const int nC = n + 2 * nw;
    int sC = 0, eC = 0;
    if (nC < N){ sC = rp[nC]; eC = rp[nC + 1]; }
    // prefetch node B's leading cs slots / norm / h-row (sB,eB arrived last iteration)
    int pB0 = 0, pB1 = 0, pB2 = 0, pB3 = 0; float niB = 0.f;
    float4 hB = make_float4(0.f,0.f,0.f,0.f);
    if (n + nw < N){
      pf4(cs, sB, eB, g, pB0, pB1, pB2, pB3);
      niB = norm_in[n + nw];
      hB = *(const float4*)(h + (size_t)(n + nw) * HIDDEN + s4);
    }

    float4 acc = gather_pre4<PRE>(cs, t, degO, sA, eA, g, s4, pA0, pA1, pA2, pA3);
    acc = xreduce4(acc);
    const size_t rowo = (size_t)n * HIDDEN;
    float4 v;
    v.x = (hA.x + acc.x * niA + bv.x) * SCALE_C;
    v.y = (hA.y + acc.y * niA + bv.y) * SCALE_C;
    v.z = (hA.z + acc.z * niA + bv.z) * SCALE_C;
    v.w = (hA.w + acc.w * niA + bv.w) * SCALE_C;
    if (g == 0){
      *(float4*)(h + rowo + s4) = v;
      if (BN){
        s1.x += v.x; s1.y += v.y; s1.z += v.z; s1.w += v.w;
        s2v.x += v.x*v.x; s2v.y += v.y*v.y; s2v.z += v.z*v.z; s2v.w += v.w*v.w;
      }
    }
    if constexpr (FUSET2){
      // h1 row replicated across groups; t2[n][lane] = (sum_k h1[k] w2[k][lane]) * norm_out[n]
      float nout = rsqrtf((float)max(degO[n], 1));
      float ta0 = 0.f, ta1 = 0.f, ta2 = 0.f, ta3 = 0.f;
      #pragma unroll
      for (int k = 0; k < 64; k += 4){
        const int ln = k >> 2;                 // source lane (0..15), compile-time
        ta0 = fmaf(rlf(v.x, ln), w2c[k],     ta0);
        ta1 = fmaf(rlf(v.y, ln), w2c[k + 1], ta1);
        ta2 = fmaf(rlf(v.z, ln), w2c[k + 2], ta2);
        ta3 = fmaf(rlf(v.w, ln), w2c[k + 3], ta3);
      }
      t2[rowo + lane] = ((ta0 + ta1) + (ta2 + ta3)) * nout;
    }
    // rotate pipeline
    sA = sB; eA = eB; pA0 = pB0; pA1 = pB1; pA2 = pB2; pA3 = pB3; niA = niB; hA = hB;
    sB = sC; eB = eC;
  }

  if (BN){
    __shared__ float l1[4][64], l2[4][64];
    const int wid = tid >> 6;
    if (g == 0){
      l1[wid][s4+0] = s1.x; l1[wid][s4+1] = s1.y; l1[wid][s4+2] = s1.z; l1[wid][s4+3] = s1.w;
      l2[wid][s4+0] = s2v.x; l2[wid][s4+1] = s2v.y; l2[wid][s4+2] = s2v.z; l2[wid][s4+3] = s2v.w;
    }
    __syncthreads();
    if (tid < 64){
      float a1 = l1[0][tid] + l1[1][tid] + l1[2][tid] + l1[3][tid];
      float a2 = l2[0][tid] + l2[1][tid] + l2[2][tid] + l2[3][tid];
      bnpart[blockIdx.x * 128 + tid] = a1;
      bnpart[blockIdx.x * 128 + 64 + tid] = a2;
    }
  }
}

// ---------- BN reduce stage 1 ----------
__global__ __launch_bounds__(256) void k_bnred(const float* __restrict__ bnpart,
    float* __restrict__ bnred, int nblk){
  int col  = threadIdx.x & 127;
  int half = threadIdx.x >> 7;
  int rows = nblk / RED_BLK;
  int r0 = blockIdx.x * rows;
  float s = 0.f;
  for (int r = half; r < rows; r += 2)
    s += bnpart[(size_t)(r0 + r) * 128 + col];
  __shared__ float sh[256];
  sh[threadIdx.x] = s;
  __syncthreads();
  if (threadIdx.x < 128)
    bnred[blockIdx.x * 128 + threadIdx.x] = sh[threadIdx.x] + sh[threadIdx.x + 128];
}

// ---------- BN finalize ----------
__global__ void k_bnfin(const float* __restrict__ bnred,
    const float* __restrict__ gamma, const float* __restrict__ beta,
    float* __restrict__ bnab, float invN){
  int c = threadIdx.x;  // 64 threads
  float s1 = 0.f, s2 = 0.f;
  #pragma unroll
  for (int b = 0; b < RED_BLK; ++b){ s1 += bnred[b*128 + c]; s2 += bnred[b*128 + 64 + c]; }
  float mu  = s1 * invN;
  float var = s2 * invN - mu * mu;               // biased variance
  float rstd = rsqrtf(var + BN_EPS);
  float sc = gamma[c] * rstd;
  bnab[c] = sc;
  bnab[64 + c] = beta[c] - mu * sc;
}

// ---------- BN apply (in place on h == d_out), float4 ----------
__global__ void k_bnapply(float* __restrict__ h, const float* __restrict__ bnab, long total4){
  long i = (long)blockIdx.x * blockDim.x + threadIdx.x;
  if (i < total4){
    int c = (int)((i * 4) & 63);
    float4 v = ((float4*)h)[i];
    v.x = fmaf(v.x, bnab[c],     bnab[64 + c]);
    v.y = fmaf(v.y, bnab[c + 1], bnab[65 + c]);
    v.z = fmaf(v.z, bnab[c + 2], bnab[66 + c]);
    v.w = fmaf(v.w, bnab[c + 3], bnab[67 + c]);
    ((float4*)h)[i] = v;
  }
}

extern "C" void kernel_launch(void* const* d_in, const int* in_sizes, int n_in,
                              void* d_out, int out_size, void* d_ws, size_t ws_size,
                              hipStream_t stream){
  const int* src = (const int*)d_in[0];
  const int* dst = (const int*)d_in[1];
  const float* x     = (const float*)d_in[2];
  const float* fc_w  = (const float*)d_in[3];
  const float* fc_b  = (const float*)d_in[4];
  const float* w1    = (const float*)d_in[5];
  const float* b1    = (const float*)d_in[6];
  const float* w2    = (const float*)d_in[7];
  const float* b2    = (const float*)d_in[8];
  const float* gamma = (const float*)d_in[9];
  const float* beta  = (const float*)d_in[10];
  const int E = in_sizes[0];
  const int N = in_sizes[2] / INFEAT;
  const int NB  = (N + 255) / 256;
  const int EB8 = (E + 2047) / 2048;          // hist/place blocks, 8 edges/thread
  const int GB  = (N + 63) / 64;              // 64-row GEMM tiles
  const int TOT = EB8 + GB;

  // h lives in d_out (fully overwritten before any read; BN apply in-place)
  float* h = (float*)d_out;

  const size_t Nh = (size_t)N * HIDDEN;
  // workspace carve (~57 MB): rank-free CSR (cursor bump-allocator instead)
  float* t        = (float*)d_ws;                       // N*64 f32
  float* t2       = t + Nh;                             // N*64 f32
  float* norm_in  = t2 + Nh;                            // N
  float* bnpart   = norm_in + N;                        // AGG_GRID*128
  float* bnred    = bnpart + AGG_GRID * 128;            // RED_BLK*128
  float* bnab     = bnred + RED_BLK * 128;              // 128
  int*   degO     = (int*)(bnab + 128);                 // N
  int*   degI     = degO + N;                           // N
  int*   rp       = degI + N;                           // N+1
  int*   cursor   = rp + N + 1;                         // N
  int*   bsum     = cursor + N;                         // 512
  int*   cs       = bsum + 512;                         // E

  // ---- zero degree arrays (degO+degI contiguous) ----
  hipMemsetAsync(degO, 0, 2 * (size_t)N * sizeof(int), stream);

  // ---- mega1: degI hist (no-return atomics) || fc GEMM + fused gemm1 (t = h@w1, unscaled) ----
  k_mega1<<<TOT, 256, 0, stream>>>(dst, degI, E,
                                   x, fc_w, fc_b, h, w1, t, N, GB, TOT);

  // ---- scans (rp + cursor) + norm_in ----
  k_scan1<<<NB, 256, 0, stream>>>(degI, bsum, N);
  k_scan2<<<1, 512, 0, stream>>>(bsum, NB);
  k_scan3<<<NB, 256, 0, stream>>>(degI, bsum, rp, cursor, norm_in, N, E);

  // ---- place: cursor-bump CSR scatter + degO histogram ----
  k_place<<<EB8, 256, 0, stream>>>(src, dst, cursor, cs, degO, E);

  // ---- conv1 aggregate + fused t2 = (h1@w2)*norm_out ----
  k_agg<false, false, true><<<AGG_GRID, 256, 0, stream>>>(
      rp, cs, t, degO, norm_in, b1, w2, h, t2, nullptr, N);
  // ---- conv2 aggregate (pre-scaled gather) + BN partials ----
  k_agg<true, true, false><<<AGG_GRID, 256, 0, stream>>>(
      rp, cs, t2, degO, norm_in, b2, nullptr, h, nullptr, bnpart, N);

  // ---- batchnorm (two-stage parallel reduction) ----
  k_bnred<<<RED_BLK, 256, 0, stream>>>(bnpart, bnred, AGG_GRID);
  k_bnfin<<<1, 64, 0, stream>>>(bnred, gamma, beta, bnab, 1.0f / (float)N);
  long total4 = (long)N * HIDDEN / 4;
  k_bnapply<<<(int)((total4 + 255) / 256), 256, 0, stream>>>(h, bnab, total4);
}

// Round 10
// 339.163 us; speedup vs baseline: 1.0720x; 1.0720x over previous
//
#include <hip/hip_runtime.h>

#define HIDDEN 64
#define INFEAT 128
#define SCALE_C 0.70710678118654752f
#define BN_EPS 1e-5f
#define AGG_GRID 2048
#define RED_BLK 32

// ---------- lane broadcast helper (uniform lane index) ----------
__device__ __forceinline__ float rlf(float v, int l){
  return __int_as_float(__builtin_amdgcn_readlane(__float_as_int(v), l));
}

// ---------- GEMM body: 64-row tile, Y[N][64] = X[N][KDIM] @ W (+B); opt fused T = Y @ W2 ----------
// 4 waves: wave w owns cols [w*16, w*16+16), row = lane. LDS 64x65 f32 (16.6KB).
template<int KDIM, bool ADDB, bool FUSET>
__device__ __forceinline__ void gemm_body(int bid, const float* __restrict__ X,
    const float* __restrict__ W, const float* __restrict__ B,
    float* __restrict__ Y, const float* __restrict__ W2, float* __restrict__ T, int N)
{
  __shared__ float smem[64 * 65];
  const int tid  = threadIdx.x;
  const int lane = tid & 63;
  const int wid  = __builtin_amdgcn_readfirstlane(tid >> 6);  // wave-uniform
  const int c0 = wid * 16;
  const int base = bid * 64;
  const int gnode = base + lane;

  float acc[16];
  #pragma unroll
  for (int c = 0; c < 16; ++c) acc[c] = ADDB ? B[c0 + c] : 0.f;

  constexpr int NCHUNK = KDIM / 32;
  #pragma unroll 1
  for (int ck = 0; ck < NCHUNK; ++ck){
    __syncthreads();
    #pragma unroll
    for (int i = 0; i < 2; ++i){
      int f  = i * 256 + tid;        // float4 id, 0..511
      int nd = f >> 3;               // 0..63
      int kq = f & 7;                // 0..7
      float4 v = make_float4(0.f, 0.f, 0.f, 0.f);
      if (base + nd < N)
        v = *(const float4*)(X + (size_t)(base + nd) * KDIM + ck * 32 + kq * 4);
      float* p = &smem[nd * 65 + kq * 4];
      p[0] = v.x; p[1] = v.y; p[2] = v.z; p[3] = v.w;
    }
    __syncthreads();
    const float* wrow = W + (size_t)ck * 32 * HIDDEN + c0;   // uniform base -> s_load
    #pragma unroll
    for (int k = 0; k < 32; ++k){
      float xv = smem[lane * 65 + k];       // bank (lane+k)%32: conflict-free
      #pragma unroll
      for (int c = 0; c < 16; ++c)
        acc[c] = fmaf(xv, wrow[k * HIDDEN + c], acc[c]);
    }
  }

  if (gnode < N){
    float4* yp = (float4*)(Y + (size_t)gnode * HIDDEN + c0);
    #pragma unroll
    for (int j = 0; j < 4; ++j)
      yp[j] = make_float4(acc[4*j], acc[4*j+1], acc[4*j+2], acc[4*j+3]);
  }

  if constexpr (FUSET){
    // h-tile exchange through the same 64x65 buffer, then T = h @ W2
    __syncthreads();                 // chunk-loop reads done
    #pragma unroll
    for (int c = 0; c < 16; ++c) smem[lane * 65 + c0 + c] = acc[c];
    __syncthreads();
    float tacc[16];
    #pragma unroll
    for (int c = 0; c < 16; ++c) tacc[c] = 0.f;
    const float* w2r = W2 + c0;
    #pragma unroll
    for (int k = 0; k < 64; ++k){
      float hv = smem[lane * 65 + k];
      #pragma unroll
      for (int c = 0; c < 16; ++c)
        tacc[c] = fmaf(hv, w2r[k * HIDDEN + c], tacc[c]);
    }
    if (gnode < N){
      float4* tp = (float4*)(T + (size_t)gnode * HIDDEN + c0);
      #pragma unroll
      for (int j = 0; j < 4; ++j)
        tp[j] = make_float4(tacc[4*j], tacc[4*j+1], tacc[4*j+2], tacc[4*j+3]);
    }
  }
}

// Bresenham role spread
__device__ __forceinline__ int role_gemm_idx(int b, int GB, int TOT, int& histIdx){
  int fb  = (int)(((long)b * GB) / TOT);
  int fb1 = (int)(((long)(b + 1) * GB) / TOT);
  histIdx = b - fb;
  return (fb1 > fb) ? fb : -1;
}

// ---------- hist: degI histogram + per-edge rank (with-return atomic), 8 edges/thread ----------
__global__ __launch_bounds__(256) void k_hist(const int* __restrict__ dst,
    int* __restrict__ degI, int* __restrict__ rank, int E){
  int e0 = blockIdx.x * 2048 + threadIdx.x;
  #pragma unroll
  for (int i = 0; i < 8; ++i){
    int e = e0 + i * 256;
    if (e < E) rank[e] = atomicAdd(&degI[dst[e]], 1);   // unique slot in dst bucket
  }
}

// ---------- mega2: CSR placement + degO hist (latency-bound, idle VALU) || fc GEMM + fused gemm1 ----------
__global__ __launch_bounds__(256) void k_mega2(const int* __restrict__ src,
    const int* __restrict__ dst, const int* __restrict__ rank,
    const int* __restrict__ rp, int* __restrict__ cs, int* __restrict__ degO, int E,
    const float* __restrict__ x, const float* __restrict__ fc_w,
    const float* __restrict__ fc_b, float* __restrict__ h,
    const float* __restrict__ w1, float* __restrict__ t, int N, int GB, int TOT){
  int pIdx;
  int g = role_gemm_idx(blockIdx.x, GB, TOT, pIdx);
  if (g >= 0) gemm_body<INFEAT, true, true>(g, x, fc_w, fc_b, h, w1, t, N);
  else {
    int e0 = pIdx * 2048 + threadIdx.x;
    #pragma unroll
    for (int i = 0; i < 8; ++i){
      int e = e0 + i * 256;
      if (e < E){
        int s = src[e];
        cs[rp[dst[e]] + rank[e]] = s;
        atomicAdd(&degO[s], 1);
      }
    }
  }
}

// ---------- scan step 1 ----------
__global__ void k_scan1(const int* __restrict__ deg, int* __restrict__ bsum, int N){
  __shared__ int sh[256];
  int t = threadIdx.x;
  int i = blockIdx.x * 256 + t;
  sh[t] = (i < N) ? deg[i] : 0;
  __syncthreads();
  for (int ofs = 128; ofs > 0; ofs >>= 1){
    if (t < ofs) sh[t] += sh[t + ofs];
    __syncthreads();
  }
  if (t == 0) bsum[blockIdx.x] = sh[0];
}

// ---------- scan step 2 ----------
__global__ void k_scan2(int* __restrict__ bsum, int NB){
  __shared__ int sh[512];
  int t = threadIdx.x;
  int v = (t < NB) ? bsum[t] : 0;
  sh[t] = v;
  __syncthreads();
  for (int ofs = 1; ofs < 512; ofs <<= 1){
    int u = (t >= ofs) ? sh[t - ofs] : 0;
    __syncthreads();
    sh[t] += u;
    __syncthreads();
  }
  if (t < NB) bsum[t] = sh[t] - v;   // exclusive
}

// ---------- scan step 3: rp + norm_in ----------
__global__ void k_scan3(const int* __restrict__ degI, const int* __restrict__ bofs,
                        int* __restrict__ rp, float* __restrict__ norm_in, int N, int E){
  __shared__ int sh[256];
  int t = threadIdx.x;
  int i = blockIdx.x * 256 + t;
  int v = (i < N) ? degI[i] : 0;
  sh[t] = v;
  __syncthreads();
  for (int ofs = 1; ofs < 256; ofs <<= 1){
    int u = (t >= ofs) ? sh[t - ofs] : 0;
    __syncthreads();
    sh[t] += u;
    __syncthreads();
  }
  if (i < N){
    int excl = sh[t] - v + bofs[blockIdx.x];
    rp[i] = excl;
    if (i == N - 1) rp[N] = E;
    norm_in[i] = rsqrtf((float)max(v, 1));
  }
}

// ---------- float4 gather, 4 prefetched cs slots (covers deg<=16 without exposed cs chain) ----------
// 16-lane group g owns slots start+g+8k (+4 partner). i0..i3 = cs at slots g,g+4,g+8,g+12,
// prefetched one node ahead by the caller. PRE=false folds rsqrt(degO[src]); PRE=true plain sum.
template<bool PRE>
__device__ __forceinline__ float4 gather_pre4(const int* __restrict__ cs,
    const float* __restrict__ t, const int* __restrict__ degO,
    int start, int end, int g, int s4, int i0, int i1, int i2, int i3)
{
  float4 acc = make_float4(0.f, 0.f, 0.f, 0.f);
  int j0 = start + g;                  // per-lane-group position; divergent, exec-masked
  if (j0 >= end) return acc;
  {                                    // iter 1: slots g, g+4 (prefetched)
    const bool b1 = (j0 + 4 < end);
    const float4 r0 = *(const float4*)(t + (size_t)i0 * HIDDEN + s4);
    const float4 r1 = *(const float4*)(t + (size_t)i1 * HIDDEN + s4);
    const float w0 = PRE ? 1.f : rsqrtf((float)degO[i0]);
    const float w1 = b1 ? (PRE ? 1.f : rsqrtf((float)degO[i1])) : 0.f;
    acc.x = fmaf(r0.x, w0, acc.x); acc.y = fmaf(r0.y, w0, acc.y);
    acc.z = fmaf(r0.z, w0, acc.z); acc.w = fmaf(r0.w, w0, acc.w);
    acc.x = fmaf(r1.x, w1, acc.x); acc.y = fmaf(r1.y, w1, acc.y);
    acc.z = fmaf(r1.z, w1, acc.z); acc.w = fmaf(r1.w, w1, acc.w);
    j0 += 8;
  }
  if (j0 >= end) return acc;
  {                                    // iter 2: slots g+8, g+12 (prefetched)
    const bool b1 = (j0 + 4 < end);
    const float4 r0 = *(const float4*)(t + (size_t)i2 * HIDDEN + s4);
    const float4 r1 = *(const float4*)(t + (size_t)i3 * HIDDEN + s4);
    const float w0 = PRE ? 1.f : rsqrtf((float)degO[i2]);
    const float w1 = b1 ? (PRE ? 1.f : rsqrtf((float)degO[i3])) : 0.f;
    acc.x = fmaf(r0.x, w0, acc.x); acc.y = fmaf(r0.y, w0, acc.y);
    acc.z = fmaf(r0.z, w0, acc.z); acc.w = fmaf(r0.w, w0, acc.w);
    acc.x = fmaf(r1.x, w1, acc.x); acc.y = fmaf(r1.y, w1, acc.y);
    acc.z = fmaf(r1.z, w1, acc.z); acc.w = fmaf(r1.w, w1, acc.w);
    j0 += 8;
  }
  while (j0 < end){                    // tail (deg>16, ~2.6% of nodes): inline cs loads
    int a0 = cs[j0];
    int a1 = (j0 + 4 < end) ? cs[j0 + 4] : a0;
    const bool b1 = (j0 + 4 < end);
    const float4 r0 = *(const float4*)(t + (size_t)a0 * HIDDEN + s4);
    const float4 r1 = *(const float4*)(t + (size_t)a1 * HIDDEN + s4);
    const float w0 = PRE ? 1.f : rsqrtf((float)degO[a0]);
    const float w1 = b1 ? (PRE ? 1.f : rsqrtf((float)degO[a1])) : 0.f;
    acc.x = fmaf(r0.x, w0, acc.x); acc.y = fmaf(r0.y, w0, acc.y);
    acc.z = fmaf(r0.z, w0, acc.z); acc.w = fmaf(r0.w, w0, acc.w);
    acc.x = fmaf(r1.x, w1, acc.x); acc.y = fmaf(r1.y, w1, acc.y);
    acc.z = fmaf(r1.z, w1, acc.z); acc.w = fmaf(r1.w, w1, acc.w);
    j0 += 8;
  }
  return acc;
}

// prefetch the 4 leading cs slots of a bucket (clamped to safe index 0, weight applied later)
__device__ __forceinline__ void pf4(const int* __restrict__ cs, int s, int e, int g,
                                    int& p0, int& p1, int& p2, int& p3){
  p0 = (s + g      < e) ? cs[s + g]      : 0;
  p1 = (s + g + 4  < e) ? cs[s + g + 4]  : 0;
  p2 = (s + g + 8  < e) ? cs[s + g + 8]  : 0;
  p3 = (s + g + 12 < e) ? cs[s + g + 12] : 0;
}

// cross-group butterfly: after this, every lane holds the full row sum for its channel-quad
__device__ __forceinline__ float4 xreduce4(float4 a){
  #pragma unroll
  for (int m = 16; m <= 32; m <<= 1){
    a.x += __shfl_xor(a.x, m, 64);
    a.y += __shfl_xor(a.y, m, 64);
    a.z += __shfl_xor(a.z, m, 64);
    a.w += __shfl_xor(a.w, m, 64);
  }
  return a;
}

// ---------- fused CSR aggregate + residual (+ BN partials) (+ fused t2 = (h1@w2)*norm_out) ----------
// Node pipeline: A = current (ctx ready), B = next (rp ready; cs/norm/h issued this iter),
// C = next-next (rp in flight). Breaks the per-node rp->cs->row chain across nodes.
template<bool BN, bool PRE, bool FUSET2>
__global__ __launch_bounds__(256, 4) void k_agg(const int* __restrict__ rp, const int* __restrict__ cs,
    const float* __restrict__ t, const int* __restrict__ degO,
    const float* __restrict__ norm_in, const float* __restrict__ b,
    const float* __restrict__ w2, float* __restrict__ h,
    float* __restrict__ t2, float* __restrict__ bnpart, int N)
{
  const int tid  = threadIdx.x;
  const int lane = tid & 63;
  const int g    = lane >> 4;        // edge-slot group 0..3
  const int s    = lane & 15;        // channel-quad 0..15
  const int s4   = s * 4;
  const int wv = (blockIdx.x * 256 + tid) >> 6;
  const int nw = (gridDim.x * 256) >> 6;
  const float4 bv = ((const float4*)b)[s];
  float4 s1 = make_float4(0.f,0.f,0.f,0.f), s2v = make_float4(0.f,0.f,0.f,0.f);

  // fastest measured epilogue form (r4): w2 column kept as VGPR array; compiler remats
  // the loads but they are L1-resident (LDS-staged variant was slower, r6).
  float w2c[64];
  if constexpr (FUSET2){
    #pragma unroll
    for (int k = 0; k < 64; ++k) w2c[k] = w2[k * HIDDEN + lane];
  }

  // ---- pipeline prologue ----
  int nA = wv;
  int sA = 0, eA = 0, pA0 = 0, pA1 = 0, pA2 = 0, pA3 = 0; float niA = 0.f;
  float4 hA = make_float4(0.f,0.f,0.f,0.f);
  if (nA < N){
    sA = rp[nA]; eA = rp[nA + 1];
    niA = norm_in[nA];
    hA = *(const float4*)(h + (size_t)nA * HIDDEN + s4);
    pf4(cs, sA, eA, g, pA0, pA1, pA2, pA3);
  }
  int nB = nA + nw;
  int sB = 0, eB = 0;
  if (nB < N){ sB = rp[nB]; eB = rp[nB + 1]; }

  for (int n = nA; n < N; n += nw){
    // issue rp for node C (two ahead) — independent, hides under this gather
    const int nC = n + 2 * nw;
    int sC = 0, eC = 0;
    if (nC < N){ sC = rp[nC]; eC = rp[nC + 1]; }
    // prefetch node B's leading cs slots / norm / h-row (sB,eB arrived last iteration)
    int pB0 = 0, pB1 = 0, pB2 = 0, pB3 = 0; float niB = 0.f;
    float4 hB = make_float4(0.f,0.f,0.f,0.f);
    if (n + nw < N){
      pf4(cs, sB, eB, g, pB0, pB1, pB2, pB3);
      niB = norm_in[n + nw];
      hB = *(const float4*)(h + (size_t)(n + nw) * HIDDEN + s4);
    }

    float4 acc = gather_pre4<PRE>(cs, t, degO, sA, eA, g, s4, pA0, pA1, pA2, pA3);
    acc = xreduce4(acc);
    const size_t rowo = (size_t)n * HIDDEN;
    float4 v;
    v.x = (hA.x + acc.x * niA + bv.x) * SCALE_C;
    v.y = (hA.y + acc.y * niA + bv.y) * SCALE_C;
    v.z = (hA.z + acc.z * niA + bv.z) * SCALE_C;
    v.w = (hA.w + acc.w * niA + bv.w) * SCALE_C;
    if (g == 0){
      *(float4*)(h + rowo + s4) = v;
      if (BN){
        s1.x += v.x; s1.y += v.y; s1.z += v.z; s1.w += v.w;
        s2v.x += v.x*v.x; s2v.y += v.y*v.y; s2v.z += v.z*v.z; s2v.w += v.w*v.w;
      }
    }
    if constexpr (FUSET2){
      // h1 row replicated across groups; t2[n][lane] = (sum_k h1[k] w2[k][lane]) * norm_out[n]
      float nout = rsqrtf((float)max(degO[n], 1));
      float ta0 = 0.f, ta1 = 0.f, ta2 = 0.f, ta3 = 0.f;
      #pragma unroll
      for (int k = 0; k < 64; k += 4){
        const int ln = k >> 2;                 // source lane (0..15), compile-time
        ta0 = fmaf(rlf(v.x, ln), w2c[k],     ta0);
        ta1 = fmaf(rlf(v.y, ln), w2c[k + 1], ta1);
        ta2 = fmaf(rlf(v.z, ln), w2c[k + 2], ta2);
        ta3 = fmaf(rlf(v.w, ln), w2c[k + 3], ta3);
      }
      t2[rowo + lane] = ((ta0 + ta1) + (ta2 + ta3)) * nout;
    }
    // rotate pipeline
    sA = sB; eA = eB; pA0 = pB0; pA1 = pB1; pA2 = pB2; pA3 = pB3; niA = niB; hA = hB;
    sB = sC; eB = eC;
  }

  if (BN){
    __shared__ float l1[4][64], l2[4][64];
    const int wid = tid >> 6;
    if (g == 0){
      l1[wid][s4+0] = s1.x; l1[wid][s4+1] = s1.y; l1[wid][s4+2] = s1.z; l1[wid][s4+3] = s1.w;
      l2[wid][s4+0] = s2v.x; l2[wid][s4+1] = s2v.y; l2[wid][s4+2] = s2v.z; l2[wid][s4+3] = s2v.w;
    }
    __syncthreads();
    if (tid < 64){
      float a1 = l1[0][tid] + l1[1][tid] + l1[2][tid] + l1[3][tid];
      float a2 = l2[0][tid] + l2[1][tid] + l2[2][tid] + l2[3][tid];
      bnpart[blockIdx.x * 128 + tid] = a1;
      bnpart[blockIdx.x * 128 + 64 + tid] = a2;
    }
  }
}

// ---------- BN reduce stage 1 ----------
__global__ __launch_bounds__(256) void k_bnred(const float* __restrict__ bnpart,
    float* __restrict__ bnred, int nblk){
  int col  = threadIdx.x & 127;
  int half = threadIdx.x >> 7;
  int rows = nblk / RED_BLK;
  int r0 = blockIdx.x * rows;
  float s = 0.f;
  for (int r = half; r < rows; r += 2)
    s += bnpart[(size_t)(r0 + r) * 128 + col];
  __shared__ float sh[256];
  sh[threadIdx.x] = s;
  __syncthreads();
  if (threadIdx.x < 128)
    bnred[blockIdx.x * 128 + threadIdx.x] = sh[threadIdx.x] + sh[threadIdx.x + 128];
}

// ---------- BN finalize ----------
__global__ void k_bnfin(const float* __restrict__ bnred,
    const float* __restrict__ gamma, const float* __restrict__ beta,
    float* __restrict__ bnab, float invN){
  int c = threadIdx.x;  // 64 threads
  float s1 = 0.f, s2 = 0.f;
  #pragma unroll
  for (int b = 0; b < RED_BLK; ++b){ s1 += bnred[b*128 + c]; s2 += bnred[b*128 + 64 + c]; }
  float mu  = s1 * invN;
  float var = s2 * invN - mu * mu;               // biased variance
  float rstd = rsqrtf(var + BN_EPS);
  float sc = gamma[c] * rstd;
  bnab[c] = sc;
  bnab[64 + c] = beta[c] - mu * sc;
}

// ---------- BN apply (in place on h == d_out), float4 ----------
__global__ void k_bnapply(float* __restrict__ h, const float* __restrict__ bnab, long total4){
  long i = (long)blockIdx.x * blockDim.x + threadIdx.x;
  if (i < total4){
    int c = (int)((i * 4) & 63);
    float4 v = ((float4*)h)[i];
    v.x = fmaf(v.x, bnab[c],     bnab[64 + c]);
    v.y = fmaf(v.y, bnab[c + 1], bnab[65 + c]);
    v.z = fmaf(v.z, bnab[c + 2], bnab[66 + c]);
    v.w = fmaf(v.w, bnab[c + 3], bnab[67 + c]);
    ((float4*)h)[i] = v;
  }
}

extern "C" void kernel_launch(void* const* d_in, const int* in_sizes, int n_in,
                              void* d_out, int out_size, void* d_ws, size_t ws_size,
                              hipStream_t stream){
  const int* src = (const int*)d_in[0];
  const int* dst = (const int*)d_in[1];
  const float* x     = (const float*)d_in[2];
  const float* fc_w  = (const float*)d_in[3];
  const float* fc_b  = (const float*)d_in[4];
  const float* w1    = (const float*)d_in[5];
  const float* b1    = (const float*)d_in[6];
  const float* w2    = (const float*)d_in[7];
  const float* b2    = (const float*)d_in[8];
  const float* gamma = (const float*)d_in[9];
  const float* beta  = (const float*)d_in[10];
  const int E = in_sizes[0];
  const int N = in_sizes[2] / INFEAT;
  const int NB  = (N + 255) / 256;
  const int EB8 = (E + 2047) / 2048;          // hist/place blocks, 8 edges/thread
  const int GB  = (N + 63) / 64;              // 64-row GEMM tiles
  const int TOT = EB8 + GB;                   // mega2 grid: place || GEMM

  // h lives in d_out (fully overwritten before any read; BN apply in-place)
  float* h = (float*)d_out;

  const size_t Nh = (size_t)N * HIDDEN;
  // workspace carve (~60 MB): rank-based CSR (r8 structure)
  float* t        = (float*)d_ws;                       // N*64 f32
  float* t2       = t + Nh;                             // N*64 f32
  float* norm_in  = t2 + Nh;                            // N
  float* bnpart   = norm_in + N;                        // AGG_GRID*128
  float* bnred    = bnpart + AGG_GRID * 128;            // RED_BLK*128
  float* bnab     = bnred + RED_BLK * 128;              // 128
  int*   degO     = (int*)(bnab + 128);                 // N
  int*   degI     = degO + N;                           // N
  int*   rp       = degI + N;                           // N+1
  int*   bsum     = rp + N + 1;                         // 512
  int*   rank     = bsum + 512;                         // E
  int*   cs       = rank + E;                           // E

  // ---- zero degree arrays (degO+degI contiguous) ----
  hipMemsetAsync(degO, 0, 2 * (size_t)N * sizeof(int), stream);

  // ---- hist: degI + ranks (atomic-floor bound, no VALU work attached) ----
  k_hist<<<EB8, 256, 0, stream>>>(dst, degI, rank, E);

  // ---- scans (rp) + norm_in ----
  k_scan1<<<NB, 256, 0, stream>>>(degI, bsum, N);
  k_scan2<<<1, 512, 0, stream>>>(bsum, NB);
  k_scan3<<<NB, 256, 0, stream>>>(degI, bsum, rp, norm_in, N, E);

  // ---- mega2: CSR place + degO hist (idle VALU) || fc GEMM + fused gemm1 (t = h@w1) ----
  k_mega2<<<TOT, 256, 0, stream>>>(src, dst, rank, rp, cs, degO, E,
                                   x, fc_w, fc_b, h, w1, t, N, GB, TOT);

  // ---- conv1 aggregate + fused t2 = (h1@w2)*norm_out ----
  k_agg<false, false, true><<<AGG_GRID, 256, 0, stream>>>(
      rp, cs, t, degO, norm_in, b1, w2, h, t2, nullptr, N);
  // ---- conv2 aggregate (pre-scaled gather) + BN partials ----
  k_agg<true, true, false><<<AGG_GRID, 256, 0, stream>>>(
      rp, cs, t2, degO, norm_in, b2, nullptr, h, nullptr, bnpart, N);

  // ---- batchnorm (two-stage parallel reduction) ----
  k_bnred<<<RED_BLK, 256, 0, stream>>>(bnpart, bnred, AGG_GRID);
  k_bnfin<<<1, 64, 0, stream>>>(bnred, gamma, beta, bnab, 1.0f / (float)N);
  long total4 = (long)N * HIDDEN / 4;
  k_bnapply<<<(int)((total4 + 255) / 256), 256, 0, stream>>>(h, bnab, total4);
}

// Round 11
// 327.310 us; speedup vs baseline: 1.1108x; 1.0362x over previous
//
#include <hip/hip_runtime.h>

#define HIDDEN 64
#define INFEAT 128
#define SCALE_C 0.70710678118654752f
#define BN_EPS 1e-5f
#define AGG_GRID 2048
#define RED_BLK 32

// ---------- lane broadcast helper (uniform lane index) ----------
__device__ __forceinline__ float rlf(float v, int l){
  return __int_as_float(__builtin_amdgcn_readlane(__float_as_int(v), l));
}

// ---------- GEMM body: 64-row tile, Y[N][64] = X[N][KDIM] @ W (+B); opt fused T = Y @ W2 ----------
// 4 waves: wave w owns cols [w*16, w*16+16), row = lane. LDS 64x65 f32 (16.6KB).
template<int KDIM, bool ADDB, bool FUSET>
__device__ __forceinline__ void gemm_body(int bid, const float* __restrict__ X,
    const float* __restrict__ W, const float* __restrict__ B,
    float* __restrict__ Y, const float* __restrict__ W2, float* __restrict__ T, int N)
{
  __shared__ float smem[64 * 65];
  const int tid  = threadIdx.x;
  const int lane = tid & 63;
  const int wid  = __builtin_amdgcn_readfirstlane(tid >> 6);  // wave-uniform
  const int c0 = wid * 16;
  const int base = bid * 64;
  const int gnode = base + lane;

  float acc[16];
  #pragma unroll
  for (int c = 0; c < 16; ++c) acc[c] = ADDB ? B[c0 + c] : 0.f;

  constexpr int NCHUNK = KDIM / 32;
  #pragma unroll 1
  for (int ck = 0; ck < NCHUNK; ++ck){
    __syncthreads();
    #pragma unroll
    for (int i = 0; i < 2; ++i){
      int f  = i * 256 + tid;        // float4 id, 0..511
      int nd = f >> 3;               // 0..63
      int kq = f & 7;                // 0..7
      float4 v = make_float4(0.f, 0.f, 0.f, 0.f);
      if (base + nd < N)
        v = *(const float4*)(X + (size_t)(base + nd) * KDIM + ck * 32 + kq * 4);
      float* p = &smem[nd * 65 + kq * 4];
      p[0] = v.x; p[1] = v.y; p[2] = v.z; p[3] = v.w;
    }
    __syncthreads();
    const float* wrow = W + (size_t)ck * 32 * HIDDEN + c0;   // uniform base -> s_load
    #pragma unroll
    for (int k = 0; k < 32; ++k){
      float xv = smem[lane * 65 + k];       // bank (lane+k)%32: conflict-free
      #pragma unroll
      for (int c = 0; c < 16; ++c)
        acc[c] = fmaf(xv, wrow[k * HIDDEN + c], acc[c]);
    }
  }

  if (gnode < N){
    float4* yp = (float4*)(Y + (size_t)gnode * HIDDEN + c0);
    #pragma unroll
    for (int j = 0; j < 4; ++j)
      yp[j] = make_float4(acc[4*j], acc[4*j+1], acc[4*j+2], acc[4*j+3]);
  }

  if constexpr (FUSET){
    // h-tile exchange through the same 64x65 buffer, then T = h @ W2
    __syncthreads();                 // chunk-loop reads done
    #pragma unroll
    for (int c = 0; c < 16; ++c) smem[lane * 65 + c0 + c] = acc[c];
    __syncthreads();
    float tacc[16];
    #pragma unroll
    for (int c = 0; c < 16; ++c) tacc[c] = 0.f;
    const float* w2r = W2 + c0;
    #pragma unroll
    for (int k = 0; k < 64; ++k){
      float hv = smem[lane * 65 + k];
      #pragma unroll
      for (int c = 0; c < 16; ++c)
        tacc[c] = fmaf(hv, w2r[k * HIDDEN + c], tacc[c]);
    }
    if (gnode < N){
      float4* tp = (float4*)(T + (size_t)gnode * HIDDEN + c0);
      #pragma unroll
      for (int j = 0; j < 4; ++j)
        tp[j] = make_float4(tacc[4*j], tacc[4*j+1], tacc[4*j+2], tacc[4*j+3]);
    }
  }
}

// Bresenham role spread
__device__ __forceinline__ int role_gemm_idx(int b, int GB, int TOT, int& histIdx){
  int fb  = (int)(((long)b * GB) / TOT);
  int fb1 = (int)(((long)(b + 1) * GB) / TOT);
  histIdx = b - fb;
  return (fb1 > fb) ? fb : -1;
}

// ---------- mega1: degI hist + ranks (8 edges/thread) || fc GEMM + fused gemm1 ----------
// r8-measured best pairing: the GEMM waves fill the hist waves' issue gaps (71us combined
// vs ~47 hist-alone + ~35 GEMM-alone); place||GEMM was additive (r10: 88us) — keep this one.
__global__ __launch_bounds__(256) void k_mega1(const int* __restrict__ dst,
    int* __restrict__ degI, int* __restrict__ rank, int E,
    const float* __restrict__ x, const float* __restrict__ fc_w,
    const float* __restrict__ fc_b, float* __restrict__ h,
    const float* __restrict__ w1, float* __restrict__ t, int N, int GB, int TOT){
  int hIdx;
  int g = role_gemm_idx(blockIdx.x, GB, TOT, hIdx);
  if (g >= 0) gemm_body<INFEAT, true, true>(g, x, fc_w, fc_b, h, w1, t, N);
  else {
    int e0 = hIdx * 2048 + threadIdx.x;
    #pragma unroll
    for (int i = 0; i < 8; ++i){
      int e = e0 + i * 256;
      if (e < E) rank[e] = atomicAdd(&degI[dst[e]], 1);   // unique slot in dst bucket
    }
  }
}

// ---------- place: atomic-free CSR placement + degO histogram (single pass, 8/thread) ----------
__global__ __launch_bounds__(256) void k_place(const int* __restrict__ src,
    const int* __restrict__ dst, const int* __restrict__ rank,
    const int* __restrict__ rp, int* __restrict__ cs, int* __restrict__ degO, int E){
  int e0 = blockIdx.x * 2048 + threadIdx.x;
  #pragma unroll
  for (int i = 0; i < 8; ++i){
    int e = e0 + i * 256;
    if (e < E){
      int s = src[e];
      cs[rp[dst[e]] + rank[e]] = s;
      atomicAdd(&degO[s], 1);
    }
  }
}

// ---------- scan step 1 ----------
__global__ void k_scan1(const int* __restrict__ deg, int* __restrict__ bsum, int N){
  __shared__ int sh[256];
  int t = threadIdx.x;
  int i = blockIdx.x * 256 + t;
  sh[t] = (i < N) ? deg[i] : 0;
  __syncthreads();
  for (int ofs = 128; ofs > 0; ofs >>= 1){
    if (t < ofs) sh[t] += sh[t + ofs];
    __syncthreads();
  }
  if (t == 0) bsum[blockIdx.x] = sh[0];
}

// ---------- scan step 2 ----------
__global__ void k_scan2(int* __restrict__ bsum, int NB){
  __shared__ int sh[512];
  int t = threadIdx.x;
  int v = (t < NB) ? bsum[t] : 0;
  sh[t] = v;
  __syncthreads();
  for (int ofs = 1; ofs < 512; ofs <<= 1){
    int u = (t >= ofs) ? sh[t - ofs] : 0;
    __syncthreads();
    sh[t] += u;
    __syncthreads();
  }
  if (t < NB) bsum[t] = sh[t] - v;   // exclusive
}

// ---------- scan step 3: rp + norm_in ----------
__global__ void k_scan3(const int* __restrict__ degI, const int* __restrict__ bofs,
                        int* __restrict__ rp, float* __restrict__ norm_in, int N, int E){
  __shared__ int sh[256];
  int t = threadIdx.x;
  int i = blockIdx.x * 256 + t;
  int v = (i < N) ? degI[i] : 0;
  sh[t] = v;
  __syncthreads();
  for (int ofs = 1; ofs < 256; ofs <<= 1){
    int u = (t >= ofs) ? sh[t - ofs] : 0;
    __syncthreads();
    sh[t] += u;
    __syncthreads();
  }
  if (i < N){
    int excl = sh[t] - v + bofs[blockIdx.x];
    rp[i] = excl;
    if (i == N - 1) rp[N] = E;
    norm_in[i] = rsqrtf((float)max(v, 1));
  }
}

// ---------- float4 gather, 4 prefetched cs slots (covers deg<=16 without exposed cs chain) ----------
// 16-lane group g owns slots start+g+8k (+4 partner). i0..i3 = cs at slots g,g+4,g+8,g+12,
// prefetched one node ahead by the caller. PRE=false folds rsqrt(degO[src]); PRE=true plain sum.
template<bool PRE>
__device__ __forceinline__ float4 gather_pre4(const int* __restrict__ cs,
    const float* __restrict__ t, const int* __restrict__ degO,
    int start, int end, int g, int s4, int i0, int i1, int i2, int i3)
{
  float4 acc = make_float4(0.f, 0.f, 0.f, 0.f);
  int j0 = start + g;                  // per-lane-group position; divergent, exec-masked
  if (j0 >= end) return acc;
  {                                    // iter 1: slots g, g+4 (prefetched)
    const bool b1 = (j0 + 4 < end);
    const float4 r0 = *(const float4*)(t + (size_t)i0 * HIDDEN + s4);
    const float4 r1 = *(const float4*)(t + (size_t)i1 * HIDDEN + s4);
    const float w0 = PRE ? 1.f : rsqrtf((float)degO[i0]);
    const float w1 = b1 ? (PRE ? 1.f : rsqrtf((float)degO[i1])) : 0.f;
    acc.x = fmaf(r0.x, w0, acc.x); acc.y = fmaf(r0.y, w0, acc.y);
    acc.z = fmaf(r0.z, w0, acc.z); acc.w = fmaf(r0.w, w0, acc.w);
    acc.x = fmaf(r1.x, w1, acc.x); acc.y = fmaf(r1.y, w1, acc.y);
    acc.z = fmaf(r1.z, w1, acc.z); acc.w = fmaf(r1.w, w1, acc.w);
    j0 += 8;
  }
  if (j0 >= end) return acc;
  {                                    // iter 2: slots g+8, g+12 (prefetched)
    const bool b1 = (j0 + 4 < end);
    const float4 r0 = *(const float4*)(t + (size_t)i2 * HIDDEN + s4);
    const float4 r1 = *(const float4*)(t + (size_t)i3 * HIDDEN + s4);
    const float w0 = PRE ? 1.f : rsqrtf((float)degO[i2]);
    const float w1 = b1 ? (PRE ? 1.f : rsqrtf((float)degO[i3])) : 0.f;
    acc.x = fmaf(r0.x, w0, acc.x); acc.y = fmaf(r0.y, w0, acc.y);
    acc.z = fmaf(r0.z, w0, acc.z); acc.w = fmaf(r0.w, w0, acc.w);
    acc.x = fmaf(r1.x, w1, acc.x); acc.y = fmaf(r1.y, w1, acc.y);
    acc.z = fmaf(r1.z, w1, acc.z); acc.w = fmaf(r1.w, w1, acc.w);
    j0 += 8;
  }
  while (j0 < end){                    // tail (deg>16, ~2.6% of nodes): inline cs loads
    int a0 = cs[j0];
    int a1 = (j0 + 4 < end) ? cs[j0 + 4] : a0;
    const bool b1 = (j0 + 4 < end);
    const float4 r0 = *(const float4*)(t + (size_t)a0 * HIDDEN + s4);
    const float4 r1 = *(const float4*)(t + (size_t)a1 * HIDDEN + s4);
    const float w0 = PRE ? 1.f : rsqrtf((float)degO[a0]);
    const float w1 = b1 ? (PRE ? 1.f : rsqrtf((float)degO[a1])) : 0.f;
    acc.x = fmaf(r0.x, w0, acc.x); acc.y = fmaf(r0.y, w0, acc.y);
    acc.z = fmaf(r0.z, w0, acc.z); acc.w = fmaf(r0.w, w0, acc.w);
    acc.x = fmaf(r1.x, w1, acc.x); acc.y = fmaf(r1.y, w1, acc.y);
    acc.z = fmaf(r1.z, w1, acc.z); acc.w = fmaf(r1.w, w1, acc.w);
    j0 += 8;
  }
  return acc;
}

// prefetch the 4 leading cs slots of a bucket (clamped to safe index 0, weight applied later)
__device__ __forceinline__ void pf4(const int* __restrict__ cs, int s, int e, int g,
                                    int& p0, int& p1, int& p2, int& p3){
  p0 = (s + g      < e) ? cs[s + g]      : 0;
  p1 = (s + g + 4  < e) ? cs[s + g + 4]  : 0;
  p2 = (s + g + 8  < e) ? cs[s + g + 8]  : 0;
  p3 = (s + g + 12 < e) ? cs[s + g + 12] : 0;
}

// cross-group butterfly: after this, every lane holds the full row sum for its channel-quad
__device__ __forceinline__ float4 xreduce4(float4 a){
  #pragma unroll
  for (int m = 16; m <= 32; m <<= 1){
    a.x += __shfl_xor(a.x, m, 64);
    a.y += __shfl_xor(a.y, m, 64);
    a.z += __shfl_xor(a.z, m, 64);
    a.w += __shfl_xor(a.w, m, 64);
  }
  return a;
}

// ---------- fused CSR aggregate + residual (+ BN partials) (+ fused t2 = (h1@w2)*norm_out) ----------
// Node pipeline: A = current (ctx ready), B = next (rp ready; cs/norm/h issued this iter),
// C = next-next (rp in flight). Breaks the per-node rp->cs->row chain across nodes.
template<bool BN, bool PRE, bool FUSET2>
__global__ __launch_bounds__(256, 4) void k_agg(const int* __restrict__ rp, const int* __restrict__ cs,
    const float* __restrict__ t, const int* __restrict__ degO,
    const float* __restrict__ norm_in, const float* __restrict__ b,
    const float* __restrict__ w2, float* __restrict__ h,
    float* __restrict__ t2, float* __restrict__ bnpart, int N)
{
  const int tid  = threadIdx.x;
  const int lane = tid & 63;
  const int g    = lane >> 4;        // edge-slot group 0..3
  const int s    = lane & 15;        // channel-quad 0..15
  const int s4   = s * 4;
  const int wv = (blockIdx.x * 256 + tid) >> 6;
  const int nw = (gridDim.x * 256) >> 6;
  const float4 bv = ((const float4*)b)[s];
  float4 s1 = make_float4(0.f,0.f,0.f,0.f), s2v = make_float4(0.f,0.f,0.f,0.f);

  // fastest measured epilogue form (r4): w2 column kept as VGPR array; compiler remats
  // the loads but they are L1-resident (LDS-staged variant was slower, r6).
  float w2c[64];
  if constexpr (FUSET2){
    #pragma unroll
    for (int k = 0; k < 64; ++k) w2c[k] = w2[k * HIDDEN + lane];
  }

  // ---- pipeline prologue ----
  int nA = wv;
  int sA = 0, eA = 0, pA0 = 0, pA1 = 0, pA2 = 0, pA3 = 0; float niA = 0.f;
  float4 hA = make_float4(0.f,0.f,0.f,0.f);
  if (nA < N){
    sA = rp[nA]; eA = rp[nA + 1];
    niA = norm_in[nA];
    hA = *(const float4*)(h + (size_t)nA * HIDDEN + s4);
    pf4(cs, sA, eA, g, pA0, pA1, pA2, pA3);
  }
  int nB = nA + nw;
  int sB = 0, eB = 0;
  if (nB < N){ sB = rp[nB]; eB = rp[nB + 1]; }

  for (int n = nA; n < N; n += nw){
    // issue rp for node C (two ahead) — independent, hides under this gather
    const int nC = n + 2 * nw;
    int sC = 0, eC = 0;
    if (nC < N){ sC = rp[nC]; eC = rp[nC + 1]; }
    // prefetch node B's leading cs slots / norm / h-row (sB,eB arrived last iteration)
    int pB0 = 0, pB1 = 0, pB2 = 0, pB3 = 0; float niB = 0.f;
    float4 hB = make_float4(0.f,0.f,0.f,0.f);
    if (n + nw < N){
      pf4(cs, sB, eB, g, pB0, pB1, pB2, pB3);
      niB = norm_in[n + nw];
      hB = *(const float4*)(h + (size_t)(n + nw) * HIDDEN + s4);
    }

    float4 acc = gather_pre4<PRE>(cs, t, degO, sA, eA, g, s4, pA0, pA1, pA2, pA3);
    acc = xreduce4(acc);
    const size_t rowo = (size_t)n * HIDDEN;
    float4 v;
    v.x = (hA.x + acc.x * niA + bv.x) * SCALE_C;
    v.y = (hA.y + acc.y * niA + bv.y) * SCALE_C;
    v.z = (hA.z + acc.z * niA + bv.z) * SCALE_C;
    v.w = (hA.w + acc.w * niA + bv.w) * SCALE_C;
    if (g == 0){
      *(float4*)(h + rowo + s4) = v;
      if (BN){
        s1.x += v.x; s1.y += v.y; s1.z += v.z; s1.w += v.w;
        s2v.x += v.x*v.x; s2v.y += v.y*v.y; s2v.z += v.z*v.z; s2v.w += v.w*v.w;
      }
    }
    if constexpr (FUSET2){
      // h1 row replicated across groups; t2[n][lane] = (sum_k h1[k] w2[k][lane]) * norm_out[n]
      float nout = rsqrtf((float)max(degO[n], 1));
      float ta0 = 0.f, ta1 = 0.f, ta2 = 0.f, ta3 = 0.f;
      #pragma unroll
      for (int k = 0; k < 64; k += 4){
        const int ln = k >> 2;                 // source lane (0..15), compile-time
        ta0 = fmaf(rlf(v.x, ln), w2c[k],     ta0);
        ta1 = fmaf(rlf(v.y, ln), w2c[k + 1], ta1);
        ta2 = fmaf(rlf(v.z, ln), w2c[k + 2], ta2);
        ta3 = fmaf(rlf(v.w, ln), w2c[k + 3], ta3);
      }
      t2[rowo + lane] = ((ta0 + ta1) + (ta2 + ta3)) * nout;
    }
    // rotate pipeline
    sA = sB; eA = eB; pA0 = pB0; pA1 = pB1; pA2 = pB2; pA3 = pB3; niA = niB; hA = hB;
    sB = sC; eB = eC;
  }

  if (BN){
    __shared__ float l1[4][64], l2[4][64];
    const int wid = tid >> 6;
    if (g == 0){
      l1[wid][s4+0] = s1.x; l1[wid][s4+1] = s1.y; l1[wid][s4+2] = s1.z; l1[wid][s4+3] = s1.w;
      l2[wid][s4+0] = s2v.x; l2[wid][s4+1] = s2v.y; l2[wid][s4+2] = s2v.z; l2[wid][s4+3] = s2v.w;
    }
    __syncthreads();
    if (tid < 64){
      float a1 = l1[0][tid] + l1[1][tid] + l1[2][tid] + l1[3][tid];
      float a2 = l2[0][tid] + l2[1][tid] + l2[2][tid] + l2[3][tid];
      bnpart[blockIdx.x * 128 + tid] = a1;
      bnpart[blockIdx.x * 128 + 64 + tid] = a2;
    }
  }
}

// ---------- BN reduce stage 1 ----------
__global__ __launch_bounds__(256) void k_bnred(const float* __restrict__ bnpart,
    float* __restrict__ bnred, int nblk){
  int col  = threadIdx.x & 127;
  int half = threadIdx.x >> 7;
  int rows = nblk / RED_BLK;
  int r0 = blockIdx.x * rows;
  float s = 0.f;
  for (int r = half; r < rows; r += 2)
    s += bnpart[(size_t)(r0 + r) * 128 + col];
  __shared__ float sh[256];
  sh[threadIdx.x] = s;
  __syncthreads();
  if (threadIdx.x < 128)
    bnred[blockIdx.x * 128 + threadIdx.x] = sh[threadIdx.x] + sh[threadIdx.x + 128];
}

// ---------- BN finalize ----------
__global__ void k_bnfin(const float* __restrict__ bnred,
    const float* __restrict__ gamma, const float* __restrict__ beta,
    float* __restrict__ bnab, float invN){
  int c = threadIdx.x;  // 64 threads
  float s1 = 0.f, s2 = 0.f;
  #pragma unroll
  for (int b = 0; b < RED_BLK; ++b){ s1 += bnred[b*128 + c]; s2 += bnred[b*128 + 64 + c]; }
  float mu  = s1 * invN;
  float var = s2 * invN - mu * mu;               // biased variance
  float rstd = rsqrtf(var + BN_EPS);
  float sc = gamma[c] * rstd;
  bnab[c] = sc;
  bnab[64 + c] = beta[c] - mu * sc;
}

// ---------- BN apply (in place on h == d_out), float4 ----------
__global__ void k_bnapply(float* __restrict__ h, const float* __restrict__ bnab, long total4){
  long i = (long)blockIdx.x * blockDim.x + threadIdx.x;
  if (i < total4){
    int c = (int)((i * 4) & 63);
    float4 v = ((float4*)h)[i];
    v.x = fmaf(v.x, bnab[c],     bnab[64 + c]);
    v.y = fmaf(v.y, bnab[c + 1], bnab[65 + c]);
    v.z = fmaf(v.z, bnab[c + 2], bnab[66 + c]);
    v.w = fmaf(v.w, bnab[c + 3], bnab[67 + c]);
    ((float4*)h)[i] = v;
  }
}

extern "C" void kernel_launch(void* const* d_in, const int* in_sizes, int n_in,
                              void* d_out, int out_size, void* d_ws, size_t ws_size,
                              hipStream_t stream){
  const int* src = (const int*)d_in[0];
  const int* dst = (const int*)d_in[1];
  const float* x     = (const float*)d_in[2];
  const float* fc_w  = (const float*)d_in[3];
  const float* fc_b  = (const float*)d_in[4];
  const float* w1    = (const float*)d_in[5];
  const float* b1    = (const float*)d_in[6];
  const float* w2    = (const float*)d_in[7];
  const float* b2    = (const float*)d_in[8];
  const float* gamma = (const float*)d_in[9];
  const float* beta  = (const float*)d_in[10];
  const int E = in_sizes[0];
  const int N = in_sizes[2] / INFEAT;
  const int NB  = (N + 255) / 256;
  const int EB8 = (E + 2047) / 2048;          // hist/place blocks, 8 edges/thread
  const int GB  = (N + 63) / 64;              // 64-row GEMM tiles
  const int TOT = EB8 + GB;

  // h lives in d_out (fully overwritten before any read; BN apply in-place)
  float* h = (float*)d_out;

  const size_t Nh = (size_t)N * HIDDEN;
  // workspace carve (~60 MB): rank-based CSR (r8 structure, measured best: 332us)
  float* t        = (float*)d_ws;                       // N*64 f32
  float* t2       = t + Nh;                             // N*64 f32
  float* norm_in  = t2 + Nh;                            // N
  float* bnpart   = norm_in + N;                        // AGG_GRID*128
  float* bnred    = bnpart + AGG_GRID * 128;            // RED_BLK*128
  float* bnab     = bnred + RED_BLK * 128;              // 128
  int*   degO     = (int*)(bnab + 128);                 // N
  int*   degI     = degO + N;                           // N
  int*   rp       = degI + N;                           // N+1
  int*   bsum     = rp + N + 1;                         // 512
  int*   rank     = bsum + 512;                         // E
  int*   cs       = rank + E;                           // E

  // ---- zero degree arrays (degO+degI contiguous) ----
  hipMemsetAsync(degO, 0, 2 * (size_t)N * sizeof(int), stream);

  // ---- mega1: degI hist + ranks || fc GEMM + fused gemm1 (t = h@w1, unscaled) ----
  k_mega1<<<TOT, 256, 0, stream>>>(dst, degI, rank, E,
                                   x, fc_w, fc_b, h, w1, t, N, GB, TOT);

  // ---- scans (rp) + norm_in ----
  k_scan1<<<NB, 256, 0, stream>>>(degI, bsum, N);
  k_scan2<<<1, 512, 0, stream>>>(bsum, NB);
  k_scan3<<<NB, 256, 0, stream>>>(degI, bsum, rp, norm_in, N, E);

  // ---- place: CSR scatter + degO histogram (one pass) ----
  k_place<<<EB8, 256, 0, stream>>>(src, dst, rank, rp, cs, degO, E);

  // ---- conv1 aggregate + fused t2 = (h1@w2)*norm_out ----
  k_agg<false, false, true><<<AGG_GRID, 256, 0, stream>>>(
      rp, cs, t, degO, norm_in, b1, w2, h, t2, nullptr, N);
  // ---- conv2 aggregate (pre-scaled gather) + BN partials ----
  k_agg<true, true, false><<<AGG_GRID, 256, 0, stream>>>(
      rp, cs, t2, degO, norm_in, b2, nullptr, h, nullptr, bnpart, N);

  // ---- batchnorm (two-stage parallel reduction) ----
  k_bnred<<<RED_BLK, 256, 0, stream>>>(bnpart, bnred, AGG_GRID);
  k_bnfin<<<1, 64, 0, stream>>>(bnred, gamma, beta, bnab, 1.0f / (float)N);
  long total4 = (long)N * HIDDEN / 4;
  k_bnapply<<<(int)((total4 + 255) / 256), 256, 0, stream>>>(h, bnab, total4);
}